// Round 5
// baseline (561.070 us; speedup 1.0000x reference)
//
#include <hip/hip_runtime.h>
#include <math.h>

#define BB 32
#define CC 256
#define OO 256
#define HW 56
#define SP (HW*HW)      // 3136
#define KK 4
#define HID 129
#define TEMP 34.0f
#define CPAD 38         // u16 per LDS slot: 32 data + 6 pad (76 B stride, odd bank stride)

typedef unsigned short u16;
typedef unsigned int uint32;
typedef __attribute__((ext_vector_type(8))) short bf16x8;
typedef __attribute__((ext_vector_type(4))) float f32x4;

__device__ __forceinline__ u16 f2bf(float f) {
    union { float f; uint32 u; } v; v.f = f;
    uint32 r = v.u + 0x7FFF + ((v.u >> 16) & 1);
    return (u16)(r >> 16);
}

// ---------------- Stage 1: fused transpose->bf16 + mix pooling ----------------
__global__ __launch_bounds__(256) void trans_pool(const float* __restrict__ x,
                                                  u16* __restrict__ xt,
                                                  float* __restrict__ pooled) {
    const int cb = blockIdx.x, b = blockIdx.y;
    const int tid = threadIdx.x;
    const int lane = tid & 63, wave = tid >> 6;
    const float* xp = x + ((size_t)b * CC + cb * 32) * SP;
    u16* xtb = xt + (size_t)(b * 8 + cb) * SP * 32;

    float psum[32], pmax[32];
    #pragma unroll
    for (int c = 0; c < 32; ++c) { psum[c] = 0.f; pmax[c] = -INFINITY; }

    for (int p0 = 0; p0 < SP; p0 += 256) {
        const int p = p0 + tid;
        const bool v = p < SP;
        const int pc = v ? p : (SP - 1);
        u16 ob[32];
        #pragma unroll
        for (int c = 0; c < 32; ++c) {
            const float vv = xp[(size_t)c * SP + pc];
            if (v) { psum[c] += vv; pmax[c] = fmaxf(pmax[c], vv); }
            ob[c] = f2bf(vv);
        }
        if (v) {
            #pragma unroll
            for (int j = 0; j < 4; ++j)
                *(bf16x8*)&xtb[(size_t)p * 32 + j * 8] = *(bf16x8*)&ob[j * 8];
        }
    }
    #pragma unroll
    for (int c = 0; c < 32; ++c) {
        #pragma unroll
        for (int off = 32; off >= 1; off >>= 1) {
            psum[c] += __shfl_xor(psum[c], off, 64);
            pmax[c] = fmaxf(pmax[c], __shfl_xor(pmax[c], off, 64));
        }
    }
    __shared__ float ssum[4][32];
    __shared__ float smax[4][32];
    if (lane == 0) {
        #pragma unroll
        for (int c = 0; c < 32; ++c) { ssum[wave][c] = psum[c]; smax[wave][c] = pmax[c]; }
    }
    __syncthreads();
    if (tid < 32) {
        const float s = ssum[0][tid] + ssum[1][tid] + ssum[2][tid] + ssum[3][tid];
        const float m = fmaxf(fmaxf(smax[0][tid], smax[1][tid]),
                              fmaxf(smax[2][tid], smax[3][tid]));
        pooled[b * (2 * CC) + cb * 32 + tid]      = s / (float)SP;
        pooled[b * (2 * CC) + CC + cb * 32 + tid] = m;
    }
}

// ---------------- Stage 2: attention MLP + softmax + agg bias ----------------
__global__ __launch_bounds__(256) void attn_kernel(const float* __restrict__ pooled,
                                                   const float* __restrict__ w1,
                                                   const float* __restrict__ w2,
                                                   const float* __restrict__ b2,
                                                   const float* __restrict__ bias_k,
                                                   float* __restrict__ attn,
                                                   float* __restrict__ agg_b) {
    const int b = blockIdx.x;
    const int tid = threadIdx.x;
    __shared__ float p[2 * CC];
    __shared__ float h[HID];
    __shared__ float a[KK];
    for (int i = tid; i < 2 * CC; i += 256) p[i] = pooled[b * 2 * CC + i];
    __syncthreads();
    if (tid < HID) {
        float s = 0.f;
        const float* w1r = w1 + (size_t)tid * (2 * CC);
        for (int c = 0; c < 2 * CC; ++c) s = fmaf(p[c], w1r[c], s);
        h[tid] = fmaxf(s, 0.f);
    }
    __syncthreads();
    if (tid == 0) {
        float lg[KK];
        float m = -INFINITY;
        for (int k = 0; k < KK; ++k) {
            float s = b2[k];
            for (int i = 0; i < HID; ++i) s = fmaf(h[i], w2[k * HID + i], s);
            lg[k] = s / TEMP;
            m = fmaxf(m, lg[k]);
        }
        float den = 0.f;
        for (int k = 0; k < KK; ++k) { lg[k] = expf(lg[k] - m); den += lg[k]; }
        for (int k = 0; k < KK; ++k) { a[k] = lg[k] / den; attn[b * KK + k] = a[k]; }
    }
    __syncthreads();
    if (tid < OO) {
        float s = 0.f;
        #pragma unroll
        for (int k = 0; k < KK; ++k) s = fmaf(a[k], bias_k[k * OO + tid], s);
        agg_b[b * OO + tid] = s;
    }
}

// ---------------- Stage 2b: aggregate weights -> bf16, layout wT[b][uv][o][c] ----
__global__ __launch_bounds__(256) void agg_kernel(const float* __restrict__ weight,
                                                  const float* __restrict__ attn,
                                                  u16* __restrict__ wT) {
    const int o = blockIdx.x;
    const int c = threadIdx.x;
    __shared__ float at[BB * KK];
    if (threadIdx.x < BB * KK) at[threadIdx.x] = attn[threadIdx.x];
    __syncthreads();
    float w[KK][9];
    #pragma unroll
    for (int k = 0; k < KK; ++k)
        #pragma unroll
        for (int uv = 0; uv < 9; ++uv)
            w[k][uv] = weight[(size_t)((k * OO + o) * CC + c) * 9 + uv];
    for (int b = 0; b < BB; ++b) {
        const float a0 = at[b*KK+0], a1 = at[b*KK+1], a2 = at[b*KK+2], a3 = at[b*KK+3];
        #pragma unroll
        for (int uv = 0; uv < 9; ++uv) {
            float s = a0 * w[0][uv] + a1 * w[1][uv] + a2 * w[2][uv] + a3 * w[3][uv];
            wT[(size_t)((b * 9 + uv) * OO + o) * CC + c] = f2bf(s);
        }
    }
}

// ---------------- Stage 3: MFMA implicit-GEMM conv ----------------
// 1-D grid of 896 blocks, XCD-pinned: b = (id&7) + 8*((id>>3)/28) keeps all
// 28 tiles of a sample on one XCD (wT[b]+x_t[b] = 2.8 MB < 4 MB L2).
// Block tile: 128 o x 224 p. 4 waves (2M x 2N), wave 64 x 112 (M_rep=4,
// N_rep=7). Double-buffered LDS (2 x 26.4 KB -> 3 blocks/CU resident) with
// register prefetch; one barrier per 32-channel chunk.
__global__ __launch_bounds__(256, 3) void conv_mfma(const u16* __restrict__ xt,
                                                    const u16* __restrict__ wT,
                                                    const float* __restrict__ agg_b,
                                                    float* __restrict__ out) {
    const int id   = blockIdx.x;
    const int g    = id >> 3;
    const int b    = (id & 7) + 8 * (g / 28);
    const int tile = g % 28;
    const int px   = tile % 14, oy = tile / 14;
    const int tid  = threadIdx.x;
    const int lane = tid & 63, wave = tid >> 6;
    const int wm = wave & 1, wn = wave >> 1;
    const int l15 = lane & 15, kg = lane >> 4;
    const int p0 = px * 224;
    const int r0 = px * 4 - 1;
    const int pbase = r0 * 56;
    const int b8 = b * 8;

    __shared__ u16 xs[2][6 * 58 * CPAD];   // 2 x 26448 B

    // zero guard columns of both buffers (never rewritten)
    if (tid < 96) {
        const int bufi = tid / 48, t = tid % 48;
        const int gg = t >> 2, q = t & 3;
        const int r = gg >> 1, side = gg & 1;
        bf16x8 z = {};
        *(bf16x8*)&xs[bufi][(r * 58 + side * 57) * CPAD + q * 8] = z;
    }

    // staging map: 336 interior slots x 4 pieces of 16B = 1344 pieces
    int ldsoff[6]; long long goff[6]; bool vld[6], act[6];
    #pragma unroll
    for (int k = 0; k < 6; ++k) {
        const int i = tid + k * 256;
        const int s = i >> 2, q = i & 3;
        const int rrel = s / 56, col = s % 56;
        const int p = pbase + s;
        act[k] = (i < 1344);
        vld[k] = act[k] && (p >= 0) && (p < SP);
        ldsoff[k] = (rrel * 58 + col + 1) * CPAD + q * 8;
        goff[k] = (long long)p * 32 + q * 8;
    }

    // B-operand LDS base (u16 units, within one buffer) per n-fragment
    int lds_base[7];
    #pragma unroll
    for (int nf = 0; nf < 7; ++nf) {
        const int n   = wn * 112 + nf * 16 + l15;
        const int rr  = n / 56 + 1;
        const int col = n % 56;
        lds_base[nf] = (rr * 58 + col + 1) * CPAD + kg * 8;
    }

    // A-operand: wT[b][uv][o][c], o = oy*128 + wm*64 + mf*16 + l15, c = c0 + kg*8
    const u16* wTb = wT + (size_t)b * 9 * OO * CC
                        + (size_t)(oy * 128 + wm * 64 + l15) * CC + kg * 8;

    f32x4 acc[4][7];
    #pragma unroll
    for (int mf = 0; mf < 4; ++mf)
        #pragma unroll
        for (int nf = 0; nf < 7; ++nf)
            acc[mf][nf] = (f32x4)0.f;

    // prologue: chunk 0 -> regs -> buf0
    {
        bf16x8 stg[6];
        const u16* xtb = xt + (size_t)b8 * SP * 32;
        #pragma unroll
        for (int k = 0; k < 6; ++k)
            if (act[k]) stg[k] = vld[k] ? *(const bf16x8*)(xtb + goff[k]) : (bf16x8)0;
        #pragma unroll
        for (int k = 0; k < 6; ++k)
            if (act[k]) *(bf16x8*)&xs[0][ldsoff[k]] = stg[k];
    }
    __syncthreads();

    for (int cb = 0; cb < 8; ++cb) {
        // issue next chunk's loads (latency hides under the 252-MFMA phase)
        bf16x8 nxt[6];
        if (cb < 7) {
            const u16* xtb = xt + (size_t)(b8 + cb + 1) * SP * 32;
            #pragma unroll
            for (int k = 0; k < 6; ++k)
                if (act[k]) nxt[k] = vld[k] ? *(const bf16x8*)(xtb + goff[k]) : (bf16x8)0;
        }

        const u16* xsb = xs[cb & 1];
        const int c0 = cb * 32;
        #pragma unroll
        for (int uv = 0; uv < 9; ++uv) {
            const int du = uv / 3 - 1, dv = uv % 3 - 1;
            const int toff = (du * 58 + dv) * CPAD;
            bf16x8 av[4];
            #pragma unroll
            for (int mf = 0; mf < 4; ++mf)
                av[mf] = *(const bf16x8*)(wTb + (size_t)uv * OO * CC + mf * 16 * CC + c0);
            #pragma unroll
            for (int nf = 0; nf < 7; ++nf) {
                const bf16x8 bv = *(const bf16x8*)&xsb[lds_base[nf] + toff];
                #pragma unroll
                for (int mf = 0; mf < 4; ++mf)
                    acc[mf][nf] = __builtin_amdgcn_mfma_f32_16x16x32_bf16(av[mf], bv, acc[mf][nf], 0, 0, 0);
            }
        }

        // write next chunk into the other buffer
        if (cb < 7) {
            #pragma unroll
            for (int k = 0; k < 6; ++k)
                if (act[k]) *(bf16x8*)&xs[(cb + 1) & 1][ldsoff[k]] = nxt[k];
        }
        __syncthreads();
    }

    // epilogue: D row = kg*4 + r (-> o), col = l15 (-> p)
    const int obase = oy * 128 + wm * 64;
    float* outb = out + (size_t)b * OO * SP;
    #pragma unroll
    for (int mf = 0; mf < 4; ++mf) {
        #pragma unroll
        for (int r = 0; r < 4; ++r) {
            const int o = obase + mf * 16 + kg * 4 + r;
            const float bias = agg_b[b * OO + o];
            #pragma unroll
            for (int nf = 0; nf < 7; ++nf) {
                const int p = p0 + wn * 112 + nf * 16 + l15;
                outb[(size_t)o * SP + p] = acc[mf][nf][r] + bias;
            }
        }
    }
}

extern "C" void kernel_launch(void* const* d_in, const int* in_sizes, int n_in,
                              void* d_out, int out_size, void* d_ws, size_t ws_size,
                              hipStream_t stream) {
    const float* x      = (const float*)d_in[0];
    const float* weight = (const float*)d_in[1];
    const float* bias_k = (const float*)d_in[2];
    const float* w1     = (const float*)d_in[3];
    const float* w2     = (const float*)d_in[4];
    const float* b2     = (const float*)d_in[5];
    float* out = (float*)d_out;

    // workspace: x_t bf16 (51.38 MB) | wT bf16 (37.75 MB) | fp32 scratch
    u16* x_t = (u16*)d_ws;
    u16* wT  = x_t + (size_t)BB * 8 * SP * 32;
    float* ws_f   = (float*)(wT + (size_t)BB * 9 * OO * CC);
    float* pooled = ws_f;
    float* attn   = ws_f + BB * 2 * CC;
    float* agg_b  = attn + BB * KK;

    trans_pool<<<dim3(8, BB), 256, 0, stream>>>(x, x_t, pooled);
    attn_kernel<<<BB, 256, 0, stream>>>(pooled, w1, w2, b2, bias_k, attn, agg_b);
    agg_kernel<<<OO, 256, 0, stream>>>(weight, attn, wT);
    conv_mfma<<<896, 256, 0, stream>>>(x_t, wT, agg_b, out);
}

// Round 7
// 224.164 us; speedup vs baseline: 2.5029x; 2.5029x over previous
//
#include <hip/hip_runtime.h>
#include <math.h>

#define BB 32
#define CC 256
#define OO 256
#define HW 56
#define SP (HW*HW)      // 3136
#define KK 4
#define HID 129
#define TEMP 34.0f
#define CPAD 40         // u16 per LDS slot: 32 data + 8 pad (80 B stride, 16B-aligned)

typedef unsigned short u16;
typedef unsigned int uint32;
typedef __attribute__((ext_vector_type(8))) short bf16x8;
typedef __attribute__((ext_vector_type(4))) float f32x4;

__device__ __forceinline__ u16 f2bf(float f) {
    union { float f; uint32 u; } v; v.f = f;
    uint32 r = v.u + 0x7FFF + ((v.u >> 16) & 1);
    return (u16)(r >> 16);
}

// ---------------- Stage 1: fused transpose->bf16 + mix pooling ----------------
__global__ __launch_bounds__(256) void trans_pool(const float* __restrict__ x,
                                                  u16* __restrict__ xt,
                                                  float* __restrict__ pooled) {
    const int cb = blockIdx.x, b = blockIdx.y;
    const int tid = threadIdx.x;
    const int lane = tid & 63, wave = tid >> 6;
    const float* xp = x + ((size_t)b * CC + cb * 32) * SP;
    u16* xtb = xt + (size_t)(b * 8 + cb) * SP * 32;

    float psum[32], pmax[32];
    #pragma unroll
    for (int c = 0; c < 32; ++c) { psum[c] = 0.f; pmax[c] = -INFINITY; }

    for (int p0 = 0; p0 < SP; p0 += 256) {
        const int p = p0 + tid;
        const bool v = p < SP;
        const int pc = v ? p : (SP - 1);
        u16 ob[32];
        #pragma unroll
        for (int c = 0; c < 32; ++c) {
            const float vv = xp[(size_t)c * SP + pc];
            if (v) { psum[c] += vv; pmax[c] = fmaxf(pmax[c], vv); }
            ob[c] = f2bf(vv);
        }
        if (v) {
            #pragma unroll
            for (int j = 0; j < 4; ++j)
                *(bf16x8*)&xtb[(size_t)p * 32 + j * 8] = *(bf16x8*)&ob[j * 8];
        }
    }
    #pragma unroll
    for (int c = 0; c < 32; ++c) {
        #pragma unroll
        for (int off = 32; off >= 1; off >>= 1) {
            psum[c] += __shfl_xor(psum[c], off, 64);
            pmax[c] = fmaxf(pmax[c], __shfl_xor(pmax[c], off, 64));
        }
    }
    __shared__ float ssum[4][32];
    __shared__ float smax[4][32];
    if (lane == 0) {
        #pragma unroll
        for (int c = 0; c < 32; ++c) { ssum[wave][c] = psum[c]; smax[wave][c] = pmax[c]; }
    }
    __syncthreads();
    if (tid < 32) {
        const float s = ssum[0][tid] + ssum[1][tid] + ssum[2][tid] + ssum[3][tid];
        const float m = fmaxf(fmaxf(smax[0][tid], smax[1][tid]),
                              fmaxf(smax[2][tid], smax[3][tid]));
        pooled[b * (2 * CC) + cb * 32 + tid]      = s / (float)SP;
        pooled[b * (2 * CC) + CC + cb * 32 + tid] = m;
    }
}

// ---------------- Stage 2: attention MLP + softmax + agg bias ----------------
__global__ __launch_bounds__(256) void attn_kernel(const float* __restrict__ pooled,
                                                   const float* __restrict__ w1,
                                                   const float* __restrict__ w2,
                                                   const float* __restrict__ b2,
                                                   const float* __restrict__ bias_k,
                                                   float* __restrict__ attn,
                                                   float* __restrict__ agg_b) {
    const int b = blockIdx.x;
    const int tid = threadIdx.x;
    __shared__ float p[2 * CC];
    __shared__ float h[HID];
    __shared__ float a[KK];
    for (int i = tid; i < 2 * CC; i += 256) p[i] = pooled[b * 2 * CC + i];
    __syncthreads();
    if (tid < HID) {
        float s = 0.f;
        const float* w1r = w1 + (size_t)tid * (2 * CC);
        for (int c = 0; c < 2 * CC; ++c) s = fmaf(p[c], w1r[c], s);
        h[tid] = fmaxf(s, 0.f);
    }
    __syncthreads();
    if (tid == 0) {
        float lg[KK];
        float m = -INFINITY;
        for (int k = 0; k < KK; ++k) {
            float s = b2[k];
            for (int i = 0; i < HID; ++i) s = fmaf(h[i], w2[k * HID + i], s);
            lg[k] = s / TEMP;
            m = fmaxf(m, lg[k]);
        }
        float den = 0.f;
        for (int k = 0; k < KK; ++k) { lg[k] = expf(lg[k] - m); den += lg[k]; }
        for (int k = 0; k < KK; ++k) { a[k] = lg[k] / den; attn[b * KK + k] = a[k]; }
    }
    __syncthreads();
    if (tid < OO) {
        float s = 0.f;
        #pragma unroll
        for (int k = 0; k < KK; ++k) s = fmaf(a[k], bias_k[k * OO + tid], s);
        agg_b[b * OO + tid] = s;
    }
}

// ---------------- Stage 2b: aggregate weights -> bf16, layout wT[b][uv][o][c] ----
__global__ __launch_bounds__(256) void agg_kernel(const float* __restrict__ weight,
                                                  const float* __restrict__ attn,
                                                  u16* __restrict__ wT) {
    const int o = blockIdx.x;
    const int c = threadIdx.x;
    __shared__ float at[BB * KK];
    if (threadIdx.x < BB * KK) at[threadIdx.x] = attn[threadIdx.x];
    __syncthreads();
    float w[KK][9];
    #pragma unroll
    for (int k = 0; k < KK; ++k)
        #pragma unroll
        for (int uv = 0; uv < 9; ++uv)
            w[k][uv] = weight[(size_t)((k * OO + o) * CC + c) * 9 + uv];
    for (int b = 0; b < BB; ++b) {
        const float a0 = at[b*KK+0], a1 = at[b*KK+1], a2 = at[b*KK+2], a3 = at[b*KK+3];
        #pragma unroll
        for (int uv = 0; uv < 9; ++uv) {
            float s = a0 * w[0][uv] + a1 * w[1][uv] + a2 * w[2][uv] + a3 * w[3][uv];
            wT[(size_t)((b * 9 + uv) * OO + o) * CC + c] = f2bf(s);
        }
    }
}

// ---------------- Stage 3: MFMA implicit-GEMM conv ----------------
// 1-D grid of 896 blocks, XCD-pinned: b = (id&7) + 8*((id>>3)/28) keeps all
// 28 tiles of a sample on one XCD (wT[b]+x_t[b] = 2.8 MB < 4 MB L2).
// Block tile: 128 o x 224 p. 4 waves (2M x 2N), wave 64 x 112 (M_rep=4,
// N_rep=7). Double-buffered LDS x-staging with register prefetch; A-fragment
// (wT) loads pipelined one uv-step ahead WITHIN each chunk (avA/avB rotate,
// reset at chunk top — 9 is odd, so a cross-chunk parity rotation is the R6
// wrap bug: uv=8's prefetch landed in avB while uv=0 consumes avA).
// NOTE: launch_bounds min-waves MUST stay 2 — acc needs 112 AGPRs; a cap of 3
// (170 unified regs) spills accumulators to scratch (R5: WRITE_SIZE x4.6).
__global__ __launch_bounds__(256, 2) void conv_mfma(const u16* __restrict__ xt,
                                                    const u16* __restrict__ wT,
                                                    const float* __restrict__ agg_b,
                                                    float* __restrict__ out) {
    const int id   = blockIdx.x;
    const int g    = id >> 3;
    const int b    = (id & 7) + 8 * (g / 28);
    const int tile = g % 28;
    const int px   = tile % 14, oy = tile / 14;
    const int tid  = threadIdx.x;
    const int lane = tid & 63, wave = tid >> 6;
    const int wm = wave & 1, wn = wave >> 1;
    const int l15 = lane & 15, kg = lane >> 4;
    const int p0 = px * 224;
    const int r0 = px * 4 - 1;
    const int pbase = r0 * 56;
    const int b8 = b * 8;

    __shared__ u16 xs[2][6 * 58 * CPAD];   // 2 x 27840 B

    // zero guard columns of both buffers (never rewritten)
    if (tid < 96) {
        const int bufi = tid / 48, t = tid % 48;
        const int gg = t >> 2, q = t & 3;
        const int r = gg >> 1, side = gg & 1;
        bf16x8 z = {};
        *(bf16x8*)&xs[bufi][(r * 58 + side * 57) * CPAD + q * 8] = z;
    }

    // staging map: 336 interior slots x 4 pieces of 16B = 1344 pieces
    int ldsoff[6]; long long goff[6]; bool vld[6], act[6];
    #pragma unroll
    for (int k = 0; k < 6; ++k) {
        const int i = tid + k * 256;
        const int s = i >> 2, q = i & 3;
        const int rrel = s / 56, col = s % 56;
        const int p = pbase + s;
        act[k] = (i < 1344);
        vld[k] = act[k] && (p >= 0) && (p < SP);
        ldsoff[k] = (rrel * 58 + col + 1) * CPAD + q * 8;
        goff[k] = (long long)p * 32 + q * 8;
    }

    // B-operand LDS base (u16 units, within one buffer) per n-fragment
    int lds_base[7];
    #pragma unroll
    for (int nf = 0; nf < 7; ++nf) {
        const int n   = wn * 112 + nf * 16 + l15;
        const int rr  = n / 56 + 1;
        const int col = n % 56;
        lds_base[nf] = (rr * 58 + col + 1) * CPAD + kg * 8;
    }

    // A-operand: wT[b][uv][o][c], o = oy*128 + wm*64 + mf*16 + l15, c = c0 + kg*8
    const u16* wTb = wT + (size_t)b * 9 * OO * CC
                        + (size_t)(oy * 128 + wm * 64 + l15) * CC + kg * 8;

    f32x4 acc[4][7];
    #pragma unroll
    for (int mf = 0; mf < 4; ++mf)
        #pragma unroll
        for (int nf = 0; nf < 7; ++nf)
            acc[mf][nf] = (f32x4)0.f;

    // prologue: x chunk 0 -> regs -> buf0
    {
        bf16x8 stg[6];
        const u16* xtb = xt + (size_t)b8 * SP * 32;
        #pragma unroll
        for (int k = 0; k < 6; ++k)
            if (act[k]) stg[k] = vld[k] ? *(const bf16x8*)(xtb + goff[k]) : (bf16x8)0;
        #pragma unroll
        for (int k = 0; k < 6; ++k)
            if (act[k]) *(bf16x8*)&xs[0][ldsoff[k]] = stg[k];
    }
    __syncthreads();

    bf16x8 avA[4], avB[4];
    for (int cb = 0; cb < 8; ++cb) {
        // issue next x-chunk's loads (latency hides under the 9 uv phases)
        bf16x8 nxt[6];
        if (cb < 7) {
            const u16* xtb = xt + (size_t)(b8 + cb + 1) * SP * 32;
            #pragma unroll
            for (int k = 0; k < 6; ++k)
                if (act[k]) nxt[k] = vld[k] ? *(const bf16x8*)(xtb + goff[k]) : (bf16x8)0;
        }

        const int c0 = cb * 32;
        // A-pipeline reset: load uv=0's fragments for this chunk (one
        // semi-exposed L2 load per ~5k-cycle chunk phase)
        #pragma unroll
        for (int mf = 0; mf < 4; ++mf)
            avA[mf] = *(const bf16x8*)(wTb + (size_t)mf * 16 * CC + c0);

        const u16* xsb = xs[cb & 1];
        #pragma unroll
        for (int uv = 0; uv < 9; ++uv) {
            // prefetch A for uv+1 into the buffer that uv+1 consumes:
            // (uv+1)&1 -> uv even: avB, uv odd: avA. No cross-chunk wrap.
            if (uv < 8) {
                #pragma unroll
                for (int mf = 0; mf < 4; ++mf) {
                    const bf16x8 v = *(const bf16x8*)(wTb + (size_t)(uv + 1) * OO * CC
                                                          + (size_t)mf * 16 * CC + c0);
                    if (uv & 1) avA[mf] = v; else avB[mf] = v;
                }
            }
            const int du = uv / 3 - 1, dv = uv % 3 - 1;
            const int toff = (du * 58 + dv) * CPAD;
            __builtin_amdgcn_s_setprio(1);
            #pragma unroll
            for (int nf = 0; nf < 7; ++nf) {
                const bf16x8 bv = *(const bf16x8*)&xsb[lds_base[nf] + toff];
                #pragma unroll
                for (int mf = 0; mf < 4; ++mf) {
                    const bf16x8 a = (uv & 1) ? avB[mf] : avA[mf];
                    acc[mf][nf] = __builtin_amdgcn_mfma_f32_16x16x32_bf16(a, bv, acc[mf][nf], 0, 0, 0);
                }
            }
            __builtin_amdgcn_s_setprio(0);
        }

        // write next x-chunk into the other buffer
        if (cb < 7) {
            #pragma unroll
            for (int k = 0; k < 6; ++k)
                if (act[k]) *(bf16x8*)&xs[(cb + 1) & 1][ldsoff[k]] = nxt[k];
        }
        __syncthreads();
    }

    // epilogue: D row = kg*4 + r (-> o), col = l15 (-> p)
    const int obase = oy * 128 + wm * 64;
    float* outb = out + (size_t)b * OO * SP;
    #pragma unroll
    for (int mf = 0; mf < 4; ++mf) {
        #pragma unroll
        for (int r = 0; r < 4; ++r) {
            const int o = obase + mf * 16 + kg * 4 + r;
            const float bias = agg_b[b * OO + o];
            #pragma unroll
            for (int nf = 0; nf < 7; ++nf) {
                const int p = p0 + wn * 112 + nf * 16 + l15;
                outb[(size_t)o * SP + p] = acc[mf][nf][r] + bias;
            }
        }
    }
}

extern "C" void kernel_launch(void* const* d_in, const int* in_sizes, int n_in,
                              void* d_out, int out_size, void* d_ws, size_t ws_size,
                              hipStream_t stream) {
    const float* x      = (const float*)d_in[0];
    const float* weight = (const float*)d_in[1];
    const float* bias_k = (const float*)d_in[2];
    const float* w1     = (const float*)d_in[3];
    const float* w2     = (const float*)d_in[4];
    const float* b2     = (const float*)d_in[5];
    float* out = (float*)d_out;

    // workspace: x_t bf16 (51.38 MB) | wT bf16 (37.75 MB) | fp32 scratch
    u16* x_t = (u16*)d_ws;
    u16* wT  = x_t + (size_t)BB * 8 * SP * 32;
    float* ws_f   = (float*)(wT + (size_t)BB * 9 * OO * CC);
    float* pooled = ws_f;
    float* attn   = ws_f + BB * 2 * CC;
    float* agg_b  = attn + BB * KK;

    trans_pool<<<dim3(8, BB), 256, 0, stream>>>(x, x_t, pooled);
    attn_kernel<<<BB, 256, 0, stream>>>(pooled, w1, w2, b2, bias_k, attn, agg_b);
    agg_kernel<<<OO, 256, 0, stream>>>(weight, attn, wT);
    conv_mfma<<<896, 256, 0, stream>>>(x_t, wT, agg_b, out);
}